// Round 1
// 591.412 us; speedup vs baseline: 1.0482x; 1.0482x over previous
//
#include <hip/hip_runtime.h>
#include <hip/hip_bf16.h>

typedef __attribute__((ext_vector_type(8))) short short8;
typedef __attribute__((ext_vector_type(4))) float floatx4;

__device__ __forceinline__ float wsum(float v){
  #pragma unroll
  for (int m = 32; m >= 1; m >>= 1) v += __shfl_xor(v, m);
  return v;
}
__device__ __forceinline__ float lrelu(float a){ return a > 0.f ? a : 0.2f * a; }
__device__ __forceinline__ float bflo(unsigned u){ return __uint_as_float(u << 16); }
__device__ __forceinline__ float bfhi(unsigned u){ return __uint_as_float(u & 0xffff0000u); }
__device__ __forceinline__ unsigned short f2bf(float f){
  __hip_bfloat16 h = __float2bfloat16(f);
  return *reinterpret_cast<unsigned short*>(&h);
}

// fused: block 0 -> we1/we2 ; blocks 1..128 -> W1t ; blocks 129..192 -> W2t
__global__ __launch_bounds__(256) void k_prep(const float* __restrict__ We1, const float* __restrict__ ae1,
                       const float* __restrict__ We2, const float* __restrict__ ae2,
                       float* __restrict__ we1, float* __restrict__ we2,
                       const float* __restrict__ W1, unsigned short* __restrict__ W1t,
                       const float* __restrict__ W2, unsigned short* __restrict__ W2t) {
  int b = blockIdx.x, t = threadIdx.x;
  if (b == 0) {
    if (t >= 64) return;
    float s1 = 0.f, s2 = 0.f;
    if (t < 60) {
      const float4* r1 = reinterpret_cast<const float4*>(We1 + t * 128);
      const float4* r2 = reinterpret_cast<const float4*>(We2 + t * 128);
      const float4* a1 = reinterpret_cast<const float4*>(ae1);
      const float4* a2 = reinterpret_cast<const float4*>(ae2);
      for (int i = 0; i < 32; ++i) {
        float4 x1 = r1[i], y1 = a1[i];
        float4 x2 = r2[i], y2 = a2[i];
        s1 += x1.x*y1.x + x1.y*y1.y + x1.z*y1.z + x1.w*y1.w;
        s2 += x2.x*y2.x + x2.y*y2.y + x2.z*y2.z + x2.w*y2.w;
      }
    }
    we1[t] = s1; we2[t] = s2;
  } else if (b <= 128) {
    int idx = (b - 1) * 256 + t;            // K=256: 32768 elems
    int k = idx >> 7, n = idx & 127;
    W1t[(size_t)n * 256 + k] = f2bf(W1[idx]);
  } else {
    int idx = (b - 129) * 256 + t;          // K=128: 16384 elems
    int k = idx >> 7, n = idx & 127;
    W2t[(size_t)n * 128 + k] = f2bf(W2[idx]);
  }
}

// per-edge slot within its destination bucket + degree counts
__global__ void k_count(const int* __restrict__ dst, int* __restrict__ degi,
                        int* __restrict__ eslot, int E) {
  int e = blockIdx.x * blockDim.x + threadIdx.x;
  if (e < E) eslot[e] = atomicAdd(degi + dst[e], 1);
}

// single-block exclusive scan, int4 vectorized, fully unrolled (no dynamic reg indexing)
__global__ __launch_bounds__(1024) void k_scan(const int* __restrict__ degi, int* __restrict__ rowptr,
                                               int N, int E) {
  __shared__ int part[1024];
  int t = threadIdx.x;
  const int CH = 52;                 // 13 * int4 ; 1024*52 = 53248 >= N
  int lo = t * CH;
  int v[52];
  int s = 0;
  #pragma unroll
  for (int i = 0; i < 13; ++i) {
    int base_i = lo + 4 * i;
    if (base_i + 4 <= N) {
      int4 q = *reinterpret_cast<const int4*>(degi + base_i);
      v[4*i+0] = q.x; v[4*i+1] = q.y; v[4*i+2] = q.z; v[4*i+3] = q.w;
      s += q.x + q.y + q.z + q.w;
    } else {
      #pragma unroll
      for (int j = 0; j < 4; ++j) {
        int idx = base_i + j;
        int x = (idx < N) ? degi[idx] : 0;
        v[4*i+j] = x; s += x;
      }
    }
  }
  part[t] = s;
  __syncthreads();
  for (int off = 1; off < 1024; off <<= 1) {
    int u = (t >= off) ? part[t - off] : 0;
    __syncthreads();
    part[t] += u;
    __syncthreads();
  }
  int base = (t == 0) ? 0 : part[t - 1];
  #pragma unroll
  for (int i = 0; i < 13; ++i) {
    int base_i = lo + 4 * i;
    if (base_i + 4 <= N) {
      int4 o;
      o.x = base; base += v[4*i+0];
      o.y = base; base += v[4*i+1];
      o.z = base; base += v[4*i+2];
      o.w = base; base += v[4*i+3];
      *reinterpret_cast<int4*>(rowptr + base_i) = o;
    } else {
      #pragma unroll
      for (int j = 0; j < 4; ++j) {
        int idx = base_i + j;
        if (idx < N) { rowptr[idx] = base; base += v[4*i+j]; }
      }
    }
  }
  if (t == 0) rowptr[N] = E;
}

// 4 lanes per edge: e-dots for both layers, atomic-free packed float4 CSR scatter
__global__ __launch_bounds__(256) void k_fill(const int* __restrict__ src, const int* __restrict__ dst,
                       const float* __restrict__ ef,
                       const float* __restrict__ we1, const float* __restrict__ we2,
                       const int* __restrict__ rowptr, const int* __restrict__ eslot,
                       float4* __restrict__ csr, int E) {
  __shared__ float w1[64], w2[64];
  int t = threadIdx.x;
  if (t < 64) { w1[t] = we1[t]; w2[t] = we2[t]; }
  __syncthreads();
  int gid = blockIdx.x * 256 + t;
  int e = gid >> 2;
  int sub = gid & 3;
  if (e >= E) return;
  const float4* row = reinterpret_cast<const float4*>(ef + (size_t)e * 60);
  float d1 = 0.f, d2 = 0.f;
  #pragma unroll
  for (int i = sub; i < 15; i += 4) {
    float4 f = row[i];
    d1 += f.x*w1[4*i] + f.y*w1[4*i+1] + f.z*w1[4*i+2] + f.w*w1[4*i+3];
    d2 += f.x*w2[4*i] + f.y*w2[4*i+1] + f.z*w2[4*i+2] + f.w*w2[4*i+3];
  }
  d1 += __shfl_xor(d1, 1); d1 += __shfl_xor(d1, 2);
  d2 += __shfl_xor(d2, 1); d2 += __shfl_xor(d2, 2);
  if (sub == 0) {
    int d = dst[e];
    int slot = rowptr[d] + eslot[e];
    float4 v;
    v.x = __int_as_float(src[e]); v.y = d1; v.z = d2; v.w = 0.f;
    csr[slot] = v;
  }
}

// MFMA GEMM: C[M,128] = A[M,K] @ Bt[128,K]^T, bf16 MFMA, fp32 accum, bf16 out.
// Fused alpha epilogue: alps[row] += C[row,:].a_src (this wave's 64-col half),
// alpd likewise; full dot completed by the two hf halves via atomicAdd.
template <int K, bool AFP32>
__global__ __launch_bounds__(256) void k_gemm(const void* __restrict__ Av, const unsigned short* __restrict__ Bt,
                                              unsigned short* __restrict__ C,
                                              const float* __restrict__ a_src, const float* __restrict__ a_dst,
                                              float* __restrict__ alps, float* __restrict__ alpd, int M) {
  int wid = (blockIdx.x * 256 + threadIdx.x) >> 6;
  int lane = threadIdx.x & 63;
  int mt = wid >> 1, hf = wid & 1;
  if (mt * 16 >= M) return;
  int r = lane & 15, quad = lane >> 4;
  int m = mt * 16 + r;
  floatx4 acc[4] = {};
  for (int k0 = 0; k0 < K; k0 += 32) {
    int kk = k0 + quad * 8;
    short8 a;
    if (AFP32) {
      const float4* ap = reinterpret_cast<const float4*>((const float*)Av + (size_t)m * K + kk);
      float4 lo = ap[0], hi = ap[1];
      union { short8 v; unsigned short u[8]; } pa;
      pa.u[0]=f2bf(lo.x); pa.u[1]=f2bf(lo.y); pa.u[2]=f2bf(lo.z); pa.u[3]=f2bf(lo.w);
      pa.u[4]=f2bf(hi.x); pa.u[5]=f2bf(hi.y); pa.u[6]=f2bf(hi.z); pa.u[7]=f2bf(hi.w);
      a = pa.v;
    } else {
      a = *reinterpret_cast<const short8*>((const unsigned short*)Av + (size_t)m * K + kk);
    }
    #pragma unroll
    for (int t = 0; t < 4; ++t) {
      short8 b = *reinterpret_cast<const short8*>(Bt + (size_t)(hf*64 + t*16 + r) * K + kk);
      acc[t] = __builtin_amdgcn_mfma_f32_16x16x32_bf16(a, b, acc[t], 0, 0, 0);
    }
  }
  // alpha epilogue: per-row partial dots over this wave's 64 columns
  float asv[4], adv[4];
  #pragma unroll
  for (int t = 0; t < 4; ++t) {
    int col = hf * 64 + t * 16 + r;
    asv[t] = a_src[col]; adv[t] = a_dst[col];
  }
  #pragma unroll
  for (int rr = 0; rr < 4; ++rr) {
    float ps = 0.f, pd = 0.f;
    #pragma unroll
    for (int t = 0; t < 4; ++t) { ps += acc[t][rr] * asv[t]; pd += acc[t][rr] * adv[t]; }
    #pragma unroll
    for (int mo = 1; mo <= 8; mo <<= 1) { ps += __shfl_xor(ps, mo); pd += __shfl_xor(pd, mo); }
    if (r == 0) {
      int row = mt * 16 + quad * 4 + rr;
      atomicAdd(alps + row, ps);
      atomicAdd(alpd + row, pd);
    }
  }
  #pragma unroll
  for (int t = 0; t < 4; ++t) {
    int col = hf * 64 + t * 16 + r;
    #pragma unroll
    for (int rr = 0; rr < 4; ++rr) {
      int row = mt * 16 + quad * 4 + rr;
      C[(size_t)row * 128 + col] = f2bf(acc[t][rr]);
    }
  }
}

// online-softmax aggregation; wave per node, 4 edge streams (quarter-wave each),
// lane owns 8 channels (uint4 = 8 bf16); 2-deep pipeline: csr record prefetched
// 2 ahead, as_/h gathers for edge j+1 issued while processing edge j.
// Defer-max: rescale only when new alpha exceeds running max by >8 (e^8 headroom).
__global__ __launch_bounds__(256) void k_agg(const int* __restrict__ rowptr, const float4* __restrict__ csr,
                      const float* __restrict__ as_, const float* __restrict__ ad_,
                      const unsigned short* __restrict__ h, const float* __restrict__ bias,
                      unsigned short* __restrict__ out, int N, int use2, int do_relu) {
  int i = (blockIdx.x * blockDim.x + threadIdx.x) >> 6;
  int lane = threadIdx.x & 63;
  if (i >= N) return;
  int st = lane >> 4;       // stream 0..3
  int q  = lane & 15;       // channel group: ch [8q, 8q+8)
  int start = rowptr[i], end = rowptr[i + 1];
  int cnt = end - start;
  float adi = ad_[i], asi = as_[i];
  float m = -3.0e38f, s = 0.f, esum = 0.f;
  float acc[8] = {};
  int idx = start + st;
  float4 cur, nx;
  float as_c = 0.f; uint4 hv_c;
  if (idx < end) {
    cur = csr[idx];
    int sv = __float_as_int(cur.x);
    as_c = as_[sv];
    hv_c = *reinterpret_cast<const uint4*>(h + (size_t)sv * 128 + q * 8);
  }
  if (idx + 4 < end) nx = csr[idx + 4];
  for (; idx < end; idx += 4) {
    float4 n2;
    if (idx + 8 < end) n2 = csr[idx + 8];
    float as_n = 0.f; uint4 hv_n;
    if (idx + 4 < end) {
      int svn = __float_as_int(nx.x);
      as_n = as_[svn];
      hv_n = *reinterpret_cast<const uint4*>(h + (size_t)svn * 128 + q * 8);
    }
    float e = use2 ? cur.z : cur.y;
    float a = lrelu(as_c + adi + e);
    esum += e;
    if (a > m + 8.f) {
      float rr = __expf(m - a);
      s *= rr;
      #pragma unroll
      for (int j = 0; j < 8; ++j) acc[j] *= rr;
      m = a;
    }
    float w = __expf(a - m);
    s += w;
    acc[0] += w * bflo(hv_c.x); acc[1] += w * bfhi(hv_c.x);
    acc[2] += w * bflo(hv_c.y); acc[3] += w * bfhi(hv_c.y);
    acc[4] += w * bflo(hv_c.z); acc[5] += w * bfhi(hv_c.z);
    acc[6] += w * bflo(hv_c.w); acc[7] += w * bfhi(hv_c.w);
    cur = nx; nx = n2; as_c = as_n; hv_c = hv_n;
  }
  // merge 4 streams: xor 16 then xor 32
  #pragma unroll
  for (int off = 16; off <= 32; off <<= 1) {
    float m_o = __shfl_xor(m, off);
    float s_o = __shfl_xor(s, off);
    float e_o = __shfl_xor(esum, off);
    float ao[8];
    #pragma unroll
    for (int j = 0; j < 8; ++j) ao[j] = __shfl_xor(acc[j], off);
    float Mn = fmaxf(m, m_o);
    float f  = __expf(m - Mn), fo = __expf(m_o - Mn);
    s = s * f + s_o * fo;
    #pragma unroll
    for (int j = 0; j < 8; ++j) acc[j] = acc[j] * f + ao[j] * fo;
    esum += e_o;
    m = Mn;
  }
  // merge self-loop
  float a_self = lrelu(asi + adi + esum / fmaxf((float)cnt, 1.f));
  float M2 = fmaxf(m, a_self);
  float g = __expf(m - M2);
  float w_self = __expf(a_self - M2);
  s = s * g + w_self;
  uint4 hs = *reinterpret_cast<const uint4*>(h + (size_t)i * 128 + q * 8);
  float hsf[8] = { bflo(hs.x), bfhi(hs.x), bflo(hs.y), bfhi(hs.y),
                   bflo(hs.z), bfhi(hs.z), bflo(hs.w), bfhi(hs.w) };
  #pragma unroll
  for (int j = 0; j < 8; ++j) acc[j] = acc[j] * g + w_self * hsf[j];
  float inv = 1.0f / s;
  float4 bv0 = *reinterpret_cast<const float4*>(bias + q * 8);
  float4 bv1 = *reinterpret_cast<const float4*>(bias + q * 8 + 4);
  float o[8];
  o[0] = acc[0]*inv + bv0.x; o[1] = acc[1]*inv + bv0.y;
  o[2] = acc[2]*inv + bv0.z; o[3] = acc[3]*inv + bv0.w;
  o[4] = acc[4]*inv + bv1.x; o[5] = acc[5]*inv + bv1.y;
  o[6] = acc[6]*inv + bv1.z; o[7] = acc[7]*inv + bv1.w;
  if (do_relu) {
    #pragma unroll
    for (int j = 0; j < 8; ++j) o[j] = fmaxf(o[j], 0.f);
  }
  if (st == 0) {
    uint4 ov;
    ov.x = (unsigned)f2bf(o[0]) | ((unsigned)f2bf(o[1]) << 16);
    ov.y = (unsigned)f2bf(o[2]) | ((unsigned)f2bf(o[3]) << 16);
    ov.z = (unsigned)f2bf(o[4]) | ((unsigned)f2bf(o[5]) << 16);
    ov.w = (unsigned)f2bf(o[6]) | ((unsigned)f2bf(o[7]) << 16);
    *reinterpret_cast<uint4*>(out + (size_t)i * 128 + q * 8) = ov;
  }
}

// decode: wave handles 2 k's; quarter-wave per (k, half); lane owns 8 channels (uint4)
__global__ void k_decode(const int* __restrict__ src, const int* __restrict__ dst,
                         const unsigned short* __restrict__ z, float* __restrict__ out, int halfE) {
  int w = (blockIdx.x * blockDim.x + threadIdx.x) >> 6;
  int lane = threadIdx.x & 63;
  int k0 = w * 2;
  if (k0 >= halfE) return;
  int sel = lane >> 4;         // 0:(k0,h0) 1:(k0,h1) 2:(k1,h0) 3:(k1,h1)
  int q = lane & 15;           // channel group [8q, 8q+8)
  int k = k0 + (sel >> 1), hh = sel & 1;
  float p = 0.f;
  if (k < halfE) {
    int e = k + hh * halfE;
    int sv = src[e], dv = dst[e];
    uint4 a = *reinterpret_cast<const uint4*>(z + (size_t)sv * 128 + q * 8);
    uint4 b = *reinterpret_cast<const uint4*>(z + (size_t)dv * 128 + q * 8);
    p = bflo(a.x)*bflo(b.x) + bfhi(a.x)*bfhi(b.x)
      + bflo(a.y)*bflo(b.y) + bfhi(a.y)*bfhi(b.y)
      + bflo(a.z)*bflo(b.z) + bfhi(a.z)*bfhi(b.z)
      + bflo(a.w)*bflo(b.w) + bfhi(a.w)*bfhi(b.w);
  }
  // sum 16 lanes + the two halves (lanes 0-31 -> k0, 32-63 -> k1)
  #pragma unroll
  for (int mo = 1; mo <= 16; mo <<= 1) p += __shfl_xor(p, mo);
  float p1 = __shfl(p, 32);
  if (lane == 0) {
    if (k0 + 2 <= halfE) {
      *reinterpret_cast<float2*>(out + k0) = make_float2(p, p1);
    } else {
      out[k0] = p;
    }
  }
}

extern "C" void kernel_launch(void* const* d_in, const int* in_sizes, int n_in,
                              void* d_out, int out_size, void* d_ws, size_t ws_size,
                              hipStream_t stream) {
  const int H = 128;
  const int N = in_sizes[0] / 256;        // 50000
  const int E = in_sizes[1] / 2;          // 800000
  const int half = E / 2;

  const float* x   = (const float*)d_in[0];
  const int* eidx  = (const int*)d_in[1];
  const float* ef  = (const float*)d_in[2];
  const float* W1  = (const float*)d_in[4];
  const float* as1 = (const float*)d_in[5];
  const float* ad1 = (const float*)d_in[6];
  const float* We1 = (const float*)d_in[7];
  const float* ae1 = (const float*)d_in[8];
  const float* b1  = (const float*)d_in[9];
  const float* W2  = (const float*)d_in[10];
  const float* as2 = (const float*)d_in[11];
  const float* ad2 = (const float*)d_in[12];
  const float* We2 = (const float*)d_in[13];
  const float* ae2 = (const float*)d_in[14];
  const float* b2  = (const float*)d_in[15];

  const int* src = eidx;
  const int* dst = eidx + E;

  size_t off = 0;
  auto alloc = [&](size_t bytes) -> void* {
    void* p = (char*)d_ws + off;
    off += (bytes + 255) & ~(size_t)255;
    return p;
  };
  float*  we1    = (float*)alloc(64 * 4);
  float*  we2    = (float*)alloc(64 * 4);
  int*    zeroblk= (int*)alloc((size_t)N * 4 * 5);   // degi + 2x(alps,alpd), one memset
  int*    degi   = zeroblk;
  float*  alps1  = (float*)(zeroblk + (size_t)N);
  float*  alpd1  = (float*)(zeroblk + (size_t)2 * N);
  float*  alps2  = (float*)(zeroblk + (size_t)3 * N);
  float*  alpd2  = (float*)(zeroblk + (size_t)4 * N);
  int*    eslot  = (int*)alloc((size_t)E * 4);
  int*    rowptr = (int*)alloc((size_t)(N + 1) * 4);
  float4* csr    = (float4*)alloc((size_t)E * 16);
  unsigned short* W1t = (unsigned short*)alloc((size_t)128 * 256 * 2);
  unsigned short* W2t = (unsigned short*)alloc((size_t)128 * 128 * 2);
  unsigned short* hA  = (unsigned short*)alloc((size_t)N * H * 2);
  unsigned short* hB  = (unsigned short*)alloc((size_t)N * H * 2);

  hipMemsetAsync(zeroblk, 0, (size_t)N * 4 * 5, stream);

  k_prep<<<193, 256, 0, stream>>>(We1, ae1, We2, ae2, we1, we2, W1, W1t, W2, W2t);
  k_count<<<(E + 255) / 256, 256, 0, stream>>>(dst, degi, eslot, E);
  k_scan<<<1, 1024, 0, stream>>>(degi, rowptr, N, E);
  k_fill<<<(E * 4 + 255) / 256, 256, 0, stream>>>(src, dst, ef, we1, we2, rowptr, eslot, csr, E);

  int gwaves = ((N + 15) / 16) * 2;
  int gblocks = (gwaves + 3) / 4;
  // ---- layer 1 ----
  k_gemm<256, true><<<gblocks, 256, 0, stream>>>(x, W1t, hA, as1, ad1, alps1, alpd1, N);
  k_agg<<<(N + 3) / 4, 256, 0, stream>>>(rowptr, csr, alps1, alpd1, hA, b1, hB, N, 0, 1);
  // ---- layer 2 ----
  k_gemm<128, false><<<gblocks, 256, 0, stream>>>(hB, W2t, hA, as2, ad2, alps2, alpd2, N);
  k_agg<<<(N + 3) / 4, 256, 0, stream>>>(rowptr, csr, alps2, alpd2, hA, b2, hB, N, 1, 0);
  // ---- decode ----
  int dwaves = (half + 1) / 2;
  k_decode<<<(dwaves + 3) / 4, 256, 0, stream>>>(src, dst, hB, (float*)d_out, half);
}

// Round 3
// 556.604 us; speedup vs baseline: 1.1137x; 1.0625x over previous
//
#include <hip/hip_runtime.h>
#include <hip/hip_bf16.h>

typedef __attribute__((ext_vector_type(8))) short short8;
typedef __attribute__((ext_vector_type(4))) float floatx4;

__device__ __forceinline__ float wsum(float v){
  #pragma unroll
  for (int m = 32; m >= 1; m >>= 1) v += __shfl_xor(v, m);
  return v;
}
__device__ __forceinline__ float lrelu(float a){ return a > 0.f ? a : 0.2f * a; }
__device__ __forceinline__ float bflo(unsigned u){ return __uint_as_float(u << 16); }
__device__ __forceinline__ float bfhi(unsigned u){ return __uint_as_float(u & 0xffff0000u); }
__device__ __forceinline__ unsigned short f2bf(float f){
  __hip_bfloat16 h = __float2bfloat16(f);
  return *reinterpret_cast<unsigned short*>(&h);
}

// ---------------- fused prep + count ----------------
// blocks [0, CB): per-edge slot within dst bucket (atomics into degi)
// block CB+0 -> we1/we2 dots ; CB+1..CB+128 -> W1t ; CB+129..CB+192 -> W2t
__global__ __launch_bounds__(256) void k_prep(const int* __restrict__ dst, int* __restrict__ degi,
                       int* __restrict__ eslot, int E, int CB,
                       const float* __restrict__ We1, const float* __restrict__ ae1,
                       const float* __restrict__ We2, const float* __restrict__ ae2,
                       float* __restrict__ we1, float* __restrict__ we2,
                       const float* __restrict__ W1, unsigned short* __restrict__ W1t,
                       const float* __restrict__ W2, unsigned short* __restrict__ W2t) {
  int t = threadIdx.x;
  if (blockIdx.x < (unsigned)CB) {
    int e = blockIdx.x * 256 + t;
    if (e < E) eslot[e] = atomicAdd(degi + dst[e], 1);
    return;
  }
  int b = blockIdx.x - CB;
  if (b == 0) {
    if (t >= 64) return;
    float s1 = 0.f, s2 = 0.f;
    if (t < 60) {
      const float4* r1 = reinterpret_cast<const float4*>(We1 + t * 128);
      const float4* r2 = reinterpret_cast<const float4*>(We2 + t * 128);
      const float4* a1 = reinterpret_cast<const float4*>(ae1);
      const float4* a2 = reinterpret_cast<const float4*>(ae2);
      for (int i = 0; i < 32; ++i) {
        float4 x1 = r1[i], y1 = a1[i];
        float4 x2 = r2[i], y2 = a2[i];
        s1 += x1.x*y1.x + x1.y*y1.y + x1.z*y1.z + x1.w*y1.w;
        s2 += x2.x*y2.x + x2.y*y2.y + x2.z*y2.z + x2.w*y2.w;
      }
    }
    we1[t] = s1; we2[t] = s2;
  } else if (b <= 128) {
    int idx = (b - 1) * 256 + t;            // K=256: 32768 elems
    int k = idx >> 7, n = idx & 127;
    W1t[(size_t)n * 256 + k] = f2bf(W1[idx]);
  } else {
    int idx = (b - 129) * 256 + t;          // K=128: 16384 elems
    int k = idx >> 7, n = idx & 127;
    W2t[(size_t)n * 128 + k] = f2bf(W2[idx]);
  }
}

// single-block exclusive scan; wave-level shfl_up scans, 2 barriers total
__global__ __launch_bounds__(1024) void k_scan(const int* __restrict__ degi, int* __restrict__ rowptr,
                                               int N, int E) {
  __shared__ int wsums[16];
  int t = threadIdx.x;
  int wave = t >> 6, lane = t & 63;
  const int CH = 52;                 // 13 * int4 ; 1024*52 = 53248 >= N
  int lo = t * CH;
  int v[52];
  int s = 0;
  #pragma unroll
  for (int i = 0; i < 13; ++i) {
    int base_i = lo + 4 * i;
    if (base_i + 4 <= N) {
      int4 q = *reinterpret_cast<const int4*>(degi + base_i);
      v[4*i+0] = q.x; v[4*i+1] = q.y; v[4*i+2] = q.z; v[4*i+3] = q.w;
      s += q.x + q.y + q.z + q.w;
    } else {
      #pragma unroll
      for (int j = 0; j < 4; ++j) {
        int idx = base_i + j;
        int x = (idx < N) ? degi[idx] : 0;
        v[4*i+j] = x; s += x;
      }
    }
  }
  int inc = s;
  #pragma unroll
  for (int off = 1; off < 64; off <<= 1) {
    int u = __shfl_up(inc, off);
    if (lane >= off) inc += u;
  }
  if (lane == 63) wsums[wave] = inc;
  __syncthreads();
  if (wave == 0) {
    int ws = (lane < 16) ? wsums[lane] : 0;
    #pragma unroll
    for (int off = 1; off < 16; off <<= 1) {
      int u = __shfl_up(ws, off);
      if (lane >= off) ws += u;
    }
    if (lane < 16) wsums[lane] = ws;
  }
  __syncthreads();
  int base = inc - s + (wave ? wsums[wave - 1] : 0);
  #pragma unroll
  for (int i = 0; i < 13; ++i) {
    int base_i = lo + 4 * i;
    if (base_i + 4 <= N) {
      int4 o;
      o.x = base; base += v[4*i+0];
      o.y = base; base += v[4*i+1];
      o.z = base; base += v[4*i+2];
      o.w = base; base += v[4*i+3];
      *reinterpret_cast<int4*>(rowptr + base_i) = o;
    } else {
      #pragma unroll
      for (int j = 0; j < 4; ++j) {
        int idx = base_i + j;
        if (idx < N) { rowptr[idx] = base; base += v[4*i+j]; }
      }
    }
  }
  if (t == 0) rowptr[N] = E;
}

// Full-width MFMA GEMM body: one wave computes C[16,128] = A[16,K] @ Bt[128,K]^T.
// Alpha epilogue: full 128-col dot with a_src/a_dst in-wave, direct store (no atomics).
template <int K, bool AFP32>
__device__ __forceinline__ void gemm_body(int wid, int lane,
    const void* __restrict__ Av, const unsigned short* __restrict__ Bt,
    unsigned short* __restrict__ C,
    const float* __restrict__ a_src, const float* __restrict__ a_dst,
    float* __restrict__ alps, float* __restrict__ alpd, int M) {
  int mt = wid;
  if (mt * 16 >= M) return;
  int r = lane & 15, quad = lane >> 4;
  int m = mt * 16 + r;
  floatx4 acc[8] = {};
  for (int k0 = 0; k0 < K; k0 += 32) {
    int kk = k0 + quad * 8;
    short8 a;
    if (AFP32) {
      const float4* ap = reinterpret_cast<const float4*>((const float*)Av + (size_t)m * K + kk);
      float4 lo = ap[0], hi = ap[1];
      union { short8 v; unsigned short u[8]; } pa;
      pa.u[0]=f2bf(lo.x); pa.u[1]=f2bf(lo.y); pa.u[2]=f2bf(lo.z); pa.u[3]=f2bf(lo.w);
      pa.u[4]=f2bf(hi.x); pa.u[5]=f2bf(hi.y); pa.u[6]=f2bf(hi.z); pa.u[7]=f2bf(hi.w);
      a = pa.v;
    } else {
      a = *reinterpret_cast<const short8*>((const unsigned short*)Av + (size_t)m * K + kk);
    }
    #pragma unroll
    for (int t = 0; t < 8; ++t) {
      short8 b = *reinterpret_cast<const short8*>(Bt + (size_t)(t*16 + r) * K + kk);
      acc[t] = __builtin_amdgcn_mfma_f32_16x16x32_bf16(a, b, acc[t], 0, 0, 0);
    }
  }
  float asv[8], adv[8];
  #pragma unroll
  for (int t = 0; t < 8; ++t) {
    int col = t * 16 + r;
    asv[t] = a_src[col]; adv[t] = a_dst[col];
  }
  #pragma unroll
  for (int rr = 0; rr < 4; ++rr) {
    float ps = 0.f, pd = 0.f;
    #pragma unroll
    for (int t = 0; t < 8; ++t) { ps += acc[t][rr] * asv[t]; pd += acc[t][rr] * adv[t]; }
    #pragma unroll
    for (int mo = 1; mo <= 8; mo <<= 1) { ps += __shfl_xor(ps, mo); pd += __shfl_xor(pd, mo); }
    if (r == 0) {
      int row = mt * 16 + quad * 4 + rr;
      alps[row] = ps;
      alpd[row] = pd;
    }
  }
  #pragma unroll
  for (int t = 0; t < 8; ++t) {
    int col = t * 16 + r;
    #pragma unroll
    for (int rr = 0; rr < 4; ++rr) {
      int row = mt * 16 + quad * 4 + rr;
      C[(size_t)row * 128 + col] = f2bf(acc[t][rr]);
    }
  }
}

template <int K, bool AFP32>
__global__ __launch_bounds__(256) void k_gemm(const void* __restrict__ Av, const unsigned short* __restrict__ Bt,
                                              unsigned short* __restrict__ C,
                                              const float* __restrict__ a_src, const float* __restrict__ a_dst,
                                              float* __restrict__ alps, float* __restrict__ alpd, int M) {
  int wid = (blockIdx.x * 256 + threadIdx.x) >> 6;
  int lane = threadIdx.x & 63;
  gemm_body<K, AFP32>(wid, lane, Av, Bt, C, a_src, a_dst, alps, alpd, M);
}

// ---------------- fused GEMM1 + CSR fill ----------------
// blocks [0, GB): full-width GEMM layer 1 (compute-bound)
// blocks [GB, GB+FB): per-edge e-dots + atomic-free packed float4 CSR scatter (BW-bound)
__global__ __launch_bounds__(256) void k_fillgemm(
                       const int* __restrict__ src, const int* __restrict__ dst,
                       const float* __restrict__ ef,
                       const float* __restrict__ we1, const float* __restrict__ we2,
                       const int* __restrict__ rowptr, const int* __restrict__ eslot,
                       float4* __restrict__ csr, int E, int GB,
                       const float* __restrict__ x, const unsigned short* __restrict__ W1t,
                       unsigned short* __restrict__ hA,
                       const float* __restrict__ a_src, const float* __restrict__ a_dst,
                       float* __restrict__ alps, float* __restrict__ alpd, int N) {
  __shared__ float w1[64], w2[64];
  int t = threadIdx.x;
  if (blockIdx.x < (unsigned)GB) {
    int wid = (blockIdx.x * 256 + t) >> 6;
    int lane = t & 63;
    gemm_body<256, true>(wid, lane, x, W1t, hA, a_src, a_dst, alps, alpd, N);
    return;
  }
  if (t < 64) { w1[t] = we1[t]; w2[t] = we2[t]; }
  __syncthreads();
  int gid = (blockIdx.x - GB) * 256 + t;
  int e = gid >> 2;
  int sub = gid & 3;
  if (e >= E) return;
  const float4* row = reinterpret_cast<const float4*>(ef + (size_t)e * 60);
  float d1 = 0.f, d2 = 0.f;
  #pragma unroll
  for (int i = sub; i < 15; i += 4) {
    float4 f = row[i];
    d1 += f.x*w1[4*i] + f.y*w1[4*i+1] + f.z*w1[4*i+2] + f.w*w1[4*i+3];
    d2 += f.x*w2[4*i] + f.y*w2[4*i+1] + f.z*w2[4*i+2] + f.w*w2[4*i+3];
  }
  d1 += __shfl_xor(d1, 1); d1 += __shfl_xor(d1, 2);
  d2 += __shfl_xor(d2, 1); d2 += __shfl_xor(d2, 2);
  if (sub == 0) {
    int d = dst[e];
    int slot = rowptr[d] + eslot[e];
    float4 v;
    v.x = __int_as_float(src[e]); v.y = d1; v.z = d2; v.w = 0.f;
    csr[slot] = v;
  }
}

// online-softmax aggregation; wave per node, 4 edge streams (quarter-wave each),
// lane owns 8 channels (uint4 = 8 bf16); 2-deep csr pipeline + 1-deep gather pipeline.
// Defer-max: rescale only when new alpha exceeds running max by >8 (e^8 headroom).
__global__ __launch_bounds__(256) void k_agg(const int* __restrict__ rowptr, const float4* __restrict__ csr,
                      const float* __restrict__ as_, const float* __restrict__ ad_,
                      const unsigned short* __restrict__ h, const float* __restrict__ bias,
                      unsigned short* __restrict__ out, int N, int use2, int do_relu) {
  int i = (blockIdx.x * blockDim.x + threadIdx.x) >> 6;
  int lane = threadIdx.x & 63;
  if (i >= N) return;
  int st = lane >> 4;       // stream 0..3
  int q  = lane & 15;       // channel group: ch [8q, 8q+8)
  int start = rowptr[i], end = rowptr[i + 1];
  int cnt = end - start;
  float adi = ad_[i], asi = as_[i];
  float m = -3.0e38f, s = 0.f, esum = 0.f;
  float acc[8] = {};
  int idx = start + st;
  float4 cur, nx;
  float as_c = 0.f; uint4 hv_c;
  if (idx < end) {
    cur = csr[idx];
    int sv = __float_as_int(cur.x);
    as_c = as_[sv];
    hv_c = *reinterpret_cast<const uint4*>(h + (size_t)sv * 128 + q * 8);
  }
  if (idx + 4 < end) nx = csr[idx + 4];
  for (; idx < end; idx += 4) {
    float4 n2;
    if (idx + 8 < end) n2 = csr[idx + 8];
    float as_n = 0.f; uint4 hv_n;
    if (idx + 4 < end) {
      int svn = __float_as_int(nx.x);
      as_n = as_[svn];
      hv_n = *reinterpret_cast<const uint4*>(h + (size_t)svn * 128 + q * 8);
    }
    float e = use2 ? cur.z : cur.y;
    float a = lrelu(as_c + adi + e);
    esum += e;
    if (a > m + 8.f) {
      float rr = __expf(m - a);
      s *= rr;
      #pragma unroll
      for (int j = 0; j < 8; ++j) acc[j] *= rr;
      m = a;
    }
    float w = __expf(a - m);
    s += w;
    acc[0] += w * bflo(hv_c.x); acc[1] += w * bfhi(hv_c.x);
    acc[2] += w * bflo(hv_c.y); acc[3] += w * bfhi(hv_c.y);
    acc[4] += w * bflo(hv_c.z); acc[5] += w * bfhi(hv_c.z);
    acc[6] += w * bflo(hv_c.w); acc[7] += w * bfhi(hv_c.w);
    cur = nx; nx = n2; as_c = as_n; hv_c = hv_n;
  }
  // merge 4 streams: xor 16 then xor 32
  #pragma unroll
  for (int off = 16; off <= 32; off <<= 1) {
    float m_o = __shfl_xor(m, off);
    float s_o = __shfl_xor(s, off);
    float e_o = __shfl_xor(esum, off);
    float ao[8];
    #pragma unroll
    for (int j = 0; j < 8; ++j) ao[j] = __shfl_xor(acc[j], off);
    float Mn = fmaxf(m, m_o);
    float f  = __expf(m - Mn), fo = __expf(m_o - Mn);
    s = s * f + s_o * fo;
    #pragma unroll
    for (int j = 0; j < 8; ++j) acc[j] = acc[j] * f + ao[j] * fo;
    esum += e_o;
    m = Mn;
  }
  // merge self-loop
  float a_self = lrelu(asi + adi + esum / fmaxf((float)cnt, 1.f));
  float M2 = fmaxf(m, a_self);
  float g = __expf(m - M2);
  float w_self = __expf(a_self - M2);
  s = s * g + w_self;
  uint4 hs = *reinterpret_cast<const uint4*>(h + (size_t)i * 128 + q * 8);
  float hsf[8] = { bflo(hs.x), bfhi(hs.x), bflo(hs.y), bfhi(hs.y),
                   bflo(hs.z), bfhi(hs.z), bflo(hs.w), bfhi(hs.w) };
  #pragma unroll
  for (int j = 0; j < 8; ++j) acc[j] = acc[j] * g + w_self * hsf[j];
  float inv = 1.0f / s;
  float4 bv0 = *reinterpret_cast<const float4*>(bias + q * 8);
  float4 bv1 = *reinterpret_cast<const float4*>(bias + q * 8 + 4);
  float o[8];
  o[0] = acc[0]*inv + bv0.x; o[1] = acc[1]*inv + bv0.y;
  o[2] = acc[2]*inv + bv0.z; o[3] = acc[3]*inv + bv0.w;
  o[4] = acc[4]*inv + bv1.x; o[5] = acc[5]*inv + bv1.y;
  o[6] = acc[6]*inv + bv1.z; o[7] = acc[7]*inv + bv1.w;
  if (do_relu) {
    #pragma unroll
    for (int j = 0; j < 8; ++j) o[j] = fmaxf(o[j], 0.f);
  }
  if (st == 0) {
    uint4 ov;
    ov.x = (unsigned)f2bf(o[0]) | ((unsigned)f2bf(o[1]) << 16);
    ov.y = (unsigned)f2bf(o[2]) | ((unsigned)f2bf(o[3]) << 16);
    ov.z = (unsigned)f2bf(o[4]) | ((unsigned)f2bf(o[5]) << 16);
    ov.w = (unsigned)f2bf(o[6]) | ((unsigned)f2bf(o[7]) << 16);
    *reinterpret_cast<uint4*>(out + (size_t)i * 128 + q * 8) = ov;
  }
}

// decode: wave handles 2 k's; quarter-wave per (k, half); lane owns 8 channels (uint4)
__global__ void k_decode(const int* __restrict__ src, const int* __restrict__ dst,
                         const unsigned short* __restrict__ z, float* __restrict__ out, int halfE) {
  int w = (blockIdx.x * blockDim.x + threadIdx.x) >> 6;
  int lane = threadIdx.x & 63;
  int k0 = w * 2;
  if (k0 >= halfE) return;
  int sel = lane >> 4;         // 0:(k0,h0) 1:(k0,h1) 2:(k1,h0) 3:(k1,h1)
  int q = lane & 15;           // channel group [8q, 8q+8)
  int k = k0 + (sel >> 1), hh = sel & 1;
  float p = 0.f;
  if (k < halfE) {
    int e = k + hh * halfE;
    int sv = src[e], dv = dst[e];
    uint4 a = *reinterpret_cast<const uint4*>(z + (size_t)sv * 128 + q * 8);
    uint4 b = *reinterpret_cast<const uint4*>(z + (size_t)dv * 128 + q * 8);
    p = bflo(a.x)*bflo(b.x) + bfhi(a.x)*bfhi(b.x)
      + bflo(a.y)*bflo(b.y) + bfhi(a.y)*bfhi(b.y)
      + bflo(a.z)*bflo(b.z) + bfhi(a.z)*bfhi(b.z)
      + bflo(a.w)*bflo(b.w) + bfhi(a.w)*bfhi(b.w);
  }
  // sum 16 lanes + the two halves (lanes 0-31 -> k0, 32-63 -> k1)
  #pragma unroll
  for (int mo = 1; mo <= 16; mo <<= 1) p += __shfl_xor(p, mo);
  float p1 = __shfl(p, 32);
  if (lane == 0) {
    if (k0 + 2 <= halfE) {
      *reinterpret_cast<float2*>(out + k0) = make_float2(p, p1);
    } else {
      out[k0] = p;
    }
  }
}

extern "C" void kernel_launch(void* const* d_in, const int* in_sizes, int n_in,
                              void* d_out, int out_size, void* d_ws, size_t ws_size,
                              hipStream_t stream) {
  const int H = 128;
  const int N = in_sizes[0] / 256;        // 50000
  const int E = in_sizes[1] / 2;          // 800000
  const int half = E / 2;

  const float* x   = (const float*)d_in[0];
  const int* eidx  = (const int*)d_in[1];
  const float* ef  = (const float*)d_in[2];
  const float* W1  = (const float*)d_in[4];
  const float* as1 = (const float*)d_in[5];
  const float* ad1 = (const float*)d_in[6];
  const float* We1 = (const float*)d_in[7];
  const float* ae1 = (const float*)d_in[8];
  const float* b1  = (const float*)d_in[9];
  const float* W2  = (const float*)d_in[10];
  const float* as2 = (const float*)d_in[11];
  const float* ad2 = (const float*)d_in[12];
  const float* We2 = (const float*)d_in[13];
  const float* ae2 = (const float*)d_in[14];
  const float* b2  = (const float*)d_in[15];

  const int* src = eidx;
  const int* dst = eidx + E;

  size_t off = 0;
  auto alloc = [&](size_t bytes) -> void* {
    void* p = (char*)d_ws + off;
    off += (bytes + 255) & ~(size_t)255;
    return p;
  };
  float*  we1    = (float*)alloc(64 * 4);
  float*  we2    = (float*)alloc(64 * 4);
  int*    degi   = (int*)alloc((size_t)N * 4);
  float*  alps   = (float*)alloc((size_t)N * 4);
  float*  alpd   = (float*)alloc((size_t)N * 4);
  int*    eslot  = (int*)alloc((size_t)E * 4);
  int*    rowptr = (int*)alloc((size_t)(N + 1) * 4);
  float4* csr    = (float4*)alloc((size_t)E * 16);
  unsigned short* W1t = (unsigned short*)alloc((size_t)128 * 256 * 2);
  unsigned short* W2t = (unsigned short*)alloc((size_t)128 * 128 * 2);
  unsigned short* hA  = (unsigned short*)alloc((size_t)N * H * 2);
  unsigned short* hB  = (unsigned short*)alloc((size_t)N * H * 2);

  hipMemsetAsync(degi, 0, (size_t)N * 4, stream);

  int CB = (E + 255) / 256;                         // count blocks
  k_prep<<<CB + 193, 256, 0, stream>>>(dst, degi, eslot, E, CB,
                                       We1, ae1, We2, ae2, we1, we2, W1, W1t, W2, W2t);
  k_scan<<<1, 1024, 0, stream>>>(degi, rowptr, N, E);

  int gwaves = (N + 15) / 16;                       // full-width waves
  int GB = (gwaves + 3) / 4;
  int FB = (E * 4 + 255) / 256;
  // ---- layer 1 GEMM (+alpha) overlapped with CSR fill ----
  k_fillgemm<<<GB + FB, 256, 0, stream>>>(src, dst, ef, we1, we2, rowptr, eslot, csr, E, GB,
                                          x, W1t, hA, as1, ad1, alps, alpd, N);
  k_agg<<<(N + 3) / 4, 256, 0, stream>>>(rowptr, csr, alps, alpd, hA, b1, hB, N, 0, 1);
  // ---- layer 2 ----
  k_gemm<128, false><<<GB, 256, 0, stream>>>(hB, W2t, hA, as2, ad2, alps, alpd, N);
  k_agg<<<(N + 3) / 4, 256, 0, stream>>>(rowptr, csr, alps, alpd, hA, b2, hB, N, 1, 0);
  // ---- decode ----
  int dwaves = (half + 1) / 2;
  k_decode<<<(dwaves + 3) / 4, 256, 0, stream>>>(src, dst, hB, (float*)d_out, half);
}